// Round 4
// baseline (1627.790 us; speedup 1.0000x reference)
//
#include <hip/hip_runtime.h>

typedef _Float16 half2f __attribute__((ext_vector_type(2)));

#define HID 128   // hidden size
#define G4  512   // 4*HID
#define DIN 64    // input dim

__device__ __forceinline__ float fdot2(half2f a, half2f b, float c) {
  return __builtin_amdgcn_fdot2(a, b, c, false);
}
__device__ __forceinline__ half2f as_h2(unsigned int u) {
  return __builtin_bit_cast(half2f, u);
}
__device__ __forceinline__ half2f mk2(float a, float b) {
  half2f r; r.x = (_Float16)a; r.y = (_Float16)b; return r;
}
__device__ __forceinline__ float sigmoidf_fast(float x) {
  return __builtin_amdgcn_rcpf(1.0f + __expf(-x));
}
__device__ __forceinline__ float tanhf_fast(float x) {
  return 2.0f * __builtin_amdgcn_rcpf(1.0f + __expf(-2.0f * x)) - 1.0f;
}
// DPP quad_perm helpers — ctrl must be an immediate => template parameter
template <int CTRL>
__device__ __forceinline__ float dpp_add(float x) {
  int m = __builtin_amdgcn_update_dpp(0, __builtin_bit_cast(int, x),
                                      CTRL, 0xF, 0xF, true);
  return x + __builtin_bit_cast(float, m);
}
template <int CTRL>
__device__ __forceinline__ float dpp_bcast(float x) {
  int m = __builtin_amdgcn_update_dpp(0, __builtin_bit_cast(int, x),
                                      CTRL, 0xF, 0xF, true);
  return __builtin_bit_cast(float, m);
}
#define QP_XOR1 0xB1  // [1,0,3,2]
#define QP_XOR2 0x4E  // [2,3,0,1]
#define QP_B0   0x00  // [0,0,0,0]
#define QP_B1   0x55  // [1,1,1,1]
#define QP_B2   0xAA  // [2,2,2,2]
#define QP_B3   0xFF  // [3,3,3,3]

// ---------------------------------------------------------------------------
// Phase 1: x_proj, stored PERMUTED: [r][unit*4 + gate] (fp16) so scan thread
// tid = j*4+q reads xp[r*512 + tid] -- one coalesced u16 per step.
// ---------------------------------------------------------------------------
__global__ __launch_bounds__(512, 2)
void xproj_kernel(const float* __restrict__ x, const float* __restrict__ Wih,
                  const float* __restrict__ bih, const float* __restrict__ bhh,
                  _Float16* __restrict__ xp, int nrows)
{
  const int gp   = threadIdx.x;          // permuted gate index
  const int unit = gp >> 2;
  const int gate = gp & 3;
  const int row  = gate * HID + unit;    // row in W_ih / bias

  half2f wi[32];
  {
    const float4* wr = (const float4*)(Wih + (size_t)row * DIN);
#pragma unroll
    for (int q = 0; q < 16; q++) {
      float4 v = wr[q];
      wi[2 * q + 0] = mk2(v.x, v.y);
      wi[2 * q + 1] = mk2(v.z, v.w);
    }
  }
  const float bias = bih[row] + bhh[row];

  __shared__ __align__(16) _Float16 xin[8 * DIN];

  const int rows_per_block = (nrows + (int)gridDim.x - 1) / (int)gridDim.x;
  const int r0 = blockIdx.x * rows_per_block;
  const int r1 = (r0 + rows_per_block < nrows) ? (r0 + rows_per_block) : nrows;

  const int rsub = threadIdx.x >> 6;  // 0..7
  const int dd   = threadIdx.x & 63;

  float vld = 0.f;
  if (r0 + rsub < nrows) vld = x[(size_t)(r0 + rsub) * DIN + dd];

  for (int r = r0; r < r1; r += 8) {
    __syncthreads();
    xin[rsub * DIN + dd] = (_Float16)vld;
    __syncthreads();
    int rn = r + 8 + rsub;
    if (rn < nrows) vld = x[(size_t)rn * DIN + dd];

    const uint4* xi4 = (const uint4*)xin;
#pragma unroll
    for (int k = 0; k < 8; k++) {
      if (r + k >= r1) break;
      const uint4* rowp = xi4 + k * (DIN / 8);
      float a[4] = {bias, 0.f, 0.f, 0.f};
#pragma unroll
      for (int q = 0; q < 8; q++) {
        uint4 hv = rowp[q];
        a[q & 3] = fdot2(as_h2(hv.x), wi[4 * q + 0], a[q & 3]);
        a[q & 3] = fdot2(as_h2(hv.y), wi[4 * q + 1], a[q & 3]);
        a[q & 3] = fdot2(as_h2(hv.z), wi[4 * q + 2], a[q & 3]);
        a[q & 3] = fdot2(as_h2(hv.w), wi[4 * q + 3], a[q & 3]);
      }
      xp[(size_t)(r + k) * G4 + gp] = (_Float16)(a[0] + a[1] + a[2] + a[3]);
    }
  }
}

// ---------------------------------------------------------------------------
// Phase 2: scan. 64 blocks x 512 threads (8 waves, 2/SIMD).
// Thread (j = tid>>2, q = tid&3): all 4 gates of unit j over K-quarter q
// (32 h elems). Quad == one j (tid = j*4+q), so DPP quad_perm xor1+xor2
// reduces the K-partials; branchless per-lane sigma/tanh activates gate q
// only; 4 quad-broadcasts regather i,f,g,o; c replicated per quad.
// One ds round-trip + one barrier per step.
// ---------------------------------------------------------------------------
__global__ __launch_bounds__(512, 2)
void lstm_scan3(const float* __restrict__ Whh,
                const float* __restrict__ h0, const float* __restrict__ c0,
                const _Float16* __restrict__ xp,
                float* __restrict__ out, int T)
{
  const int tid = threadIdx.x;
  const int j   = tid >> 2;
  const int q   = tid & 3;
  const int b   = blockIdx.x;

  // W_hh rows gate*128+j, cols [32q, 32q+32) -> 4 gates x 16 half2 = 64 VGPR
  half2f w[4][16];
#pragma unroll
  for (int g = 0; g < 4; g++) {
    const float4* wr = (const float4*)(Whh + (size_t)(g * HID + j) * HID + q * 32);
#pragma unroll
    for (int p = 0; p < 8; p++) {
      float4 v = wr[p];
      w[g][2 * p + 0] = mk2(v.x, v.y);
      w[g][2 * p + 1] = mk2(v.z, v.w);
    }
  }

  // per-lane constants
  float selm[4];
#pragma unroll
  for (int g = 0; g < 4; g++) selm[g] = (q == g) ? 1.f : 0.f;
  const float kk = (q == 2) ? -2.f : -1.f;   // tanh gate uses exp(-2x)
  const float mm = (q == 2) ? 2.f : 1.f;
  const float bb = (q == 2) ? -1.f : 0.f;

  __shared__ __align__(16) _Float16 h_sh[2][HID];

  float c = c0[(size_t)b * HID + j];
  if (q == 0) h_sh[0][j] = (_Float16)h0[(size_t)b * HID + j];
  __syncthreads();

  const size_t xbase = (size_t)b * T * G4 + tid;   // [t][j*4+q]
  float xv = (float)xp[xbase];

  const _Float16* rb = h_sh[0];
  _Float16*       wb = h_sh[1];

  for (int t = 0; t < T; ++t) {
    float xv_next = 0.f;
    if (t + 1 < T) xv_next = (float)xp[xbase + (size_t)(t + 1) * G4];

    // my K-quarter of h: 4x ds_read_b128, all in flight
    uint4 hv[4];
    const uint4* h4 = (const uint4*)(rb + q * 32);
#pragma unroll
    for (int p = 0; p < 4; p++) hv[p] = h4[p];

    float a0 = 0.f, a1 = 0.f, a2 = 0.f, a3 = 0.f;
#pragma unroll
    for (int p = 0; p < 4; p++) {
      unsigned int d0 = hv[p].x, d1 = hv[p].y, d2 = hv[p].z, d3 = hv[p].w;
      a0 = fdot2(as_h2(d0), w[0][4 * p + 0], a0);
      a1 = fdot2(as_h2(d0), w[1][4 * p + 0], a1);
      a2 = fdot2(as_h2(d0), w[2][4 * p + 0], a2);
      a3 = fdot2(as_h2(d0), w[3][4 * p + 0], a3);
      a0 = fdot2(as_h2(d1), w[0][4 * p + 1], a0);
      a1 = fdot2(as_h2(d1), w[1][4 * p + 1], a1);
      a2 = fdot2(as_h2(d1), w[2][4 * p + 1], a2);
      a3 = fdot2(as_h2(d1), w[3][4 * p + 1], a3);
      a0 = fdot2(as_h2(d2), w[0][4 * p + 2], a0);
      a1 = fdot2(as_h2(d2), w[1][4 * p + 2], a1);
      a2 = fdot2(as_h2(d2), w[2][4 * p + 2], a2);
      a3 = fdot2(as_h2(d2), w[3][4 * p + 2], a3);
      a0 = fdot2(as_h2(d3), w[0][4 * p + 3], a0);
      a1 = fdot2(as_h2(d3), w[1][4 * p + 3], a1);
      a2 = fdot2(as_h2(d3), w[2][4 * p + 3], a2);
      a3 = fdot2(as_h2(d3), w[3][4 * p + 3], a3);
    }

    // add x_proj once per gate: lane q carries gate q's xp
    a0 = fmaf(xv, selm[0], a0);
    a1 = fmaf(xv, selm[1], a1);
    a2 = fmaf(xv, selm[2], a2);
    a3 = fmaf(xv, selm[3], a3);

    // quad reduction over K-quarters (VALU-only)
    a0 = dpp_add<QP_XOR1>(a0); a0 = dpp_add<QP_XOR2>(a0);
    a1 = dpp_add<QP_XOR1>(a1); a1 = dpp_add<QP_XOR2>(a1);
    a2 = dpp_add<QP_XOR1>(a2); a2 = dpp_add<QP_XOR2>(a2);
    a3 = dpp_add<QP_XOR1>(a3); a3 = dpp_add<QP_XOR2>(a3);

    // own-gate select (2-bit mux) + branchless activation:
    // act = mm * rcp(1 + exp(kk*x)) + bb   (sigmoid / tanh per lane consts)
    float a01 = (q & 1) ? a1 : a0;
    float a23 = (q & 1) ? a3 : a2;
    float aq  = (q & 2) ? a23 : a01;
    float act = fmaf(mm, __builtin_amdgcn_rcpf(1.0f + __expf(kk * aq)), bb);

    // regather i,f,g,o within the quad
    float gi = dpp_bcast<QP_B0>(act);
    float gf = dpp_bcast<QP_B1>(act);
    float gg = dpp_bcast<QP_B2>(act);
    float go = dpp_bcast<QP_B3>(act);

    c = gf * c + gi * gg;                // replicated per quad (bit-identical)
    float h = go * tanhf_fast(c);

    if (q == 0) wb[j] = (_Float16)h;
    if (q == 1) out[((size_t)b * T + t) * HID + j] = h;
    __syncthreads();                     // single barrier per step
    const _Float16* tmp = rb; rb = wb; wb = (_Float16*)tmp;
    xv = xv_next;
  }
}

// ---------------------------------------------------------------------------
// Fallback (ws too small): inline x-proj, round-1 structure.
// ---------------------------------------------------------------------------
__global__ __launch_bounds__(512, 2)
void lstm_scan_fb(const float* __restrict__ x, const float* __restrict__ Wih,
                  const float* __restrict__ Whh,
                  const float* __restrict__ bih, const float* __restrict__ bhh,
                  const float* __restrict__ h0, const float* __restrict__ c0,
                  float* __restrict__ out, int T)
{
  const int g = threadIdx.x;
  const int b = blockIdx.x;

  half2f w[64];
  {
    const float4* wr = (const float4*)(Whh + (size_t)g * HID);
#pragma unroll
    for (int q = 0; q < 32; q++) {
      float4 v = wr[q];
      w[2 * q + 0] = mk2(v.x, v.y);
      w[2 * q + 1] = mk2(v.z, v.w);
    }
  }
  half2f wi[32];
  float bias;
  {
    const float4* wr = (const float4*)(Wih + (size_t)g * DIN);
#pragma unroll
    for (int q = 0; q < 16; q++) {
      float4 v = wr[q];
      wi[2 * q + 0] = mk2(v.x, v.y);
      wi[2 * q + 1] = mk2(v.z, v.w);
    }
    bias = bih[g] + bhh[g];
  }

  __shared__ __align__(16) _Float16 h_sh[HID];
  __shared__ __align__(16) _Float16 xin[DIN];
  __shared__ float pre[G4];

  float c = 0.f;
  if (g < HID) {
    c = c0[(size_t)b * HID + g];
    h_sh[g] = (_Float16)h0[(size_t)b * HID + g];
  }
  if (g < DIN) xin[g] = (_Float16)x[((size_t)b * T) * DIN + g];
  __syncthreads();

  const bool is_tanh_gate = (g >= 2 * HID) && (g < 3 * HID);

  for (int t = 0; t < T; ++t) {
    float a[4] = {0.f, 0.f, 0.f, 0.f};
    const uint4* h4 = (const uint4*)h_sh;
#pragma unroll
    for (int q = 0; q < 16; q++) {
      uint4 hv = h4[q];
      a[q & 3] = fdot2(as_h2(hv.x), w[4 * q + 0], a[q & 3]);
      a[q & 3] = fdot2(as_h2(hv.y), w[4 * q + 1], a[q & 3]);
      a[q & 3] = fdot2(as_h2(hv.z), w[4 * q + 2], a[q & 3]);
      a[q & 3] = fdot2(as_h2(hv.w), w[4 * q + 3], a[q & 3]);
    }
    const uint4* x4 = (const uint4*)xin;
#pragma unroll
    for (int q = 0; q < 8; q++) {
      uint4 hv = x4[q];
      a[q & 3] = fdot2(as_h2(hv.x), wi[4 * q + 0], a[q & 3]);
      a[q & 3] = fdot2(as_h2(hv.y), wi[4 * q + 1], a[q & 3]);
      a[q & 3] = fdot2(as_h2(hv.z), wi[4 * q + 2], a[q & 3]);
      a[q & 3] = fdot2(as_h2(hv.w), wi[4 * q + 3], a[q & 3]);
    }
    float preact = a[0] + a[1] + a[2] + a[3] + bias;
    float act = is_tanh_gate ? tanhf_fast(preact) : sigmoidf_fast(preact);
    pre[g] = act;
    __syncthreads();

    if (g < HID) {
      float i  = pre[g];
      float f  = pre[g + HID];
      float gg = pre[g + 2 * HID];
      float o  = pre[g + 3 * HID];
      c = f * c + i * gg;
      float h = o * tanhf_fast(c);
      out[((size_t)b * T + t) * HID + g] = h;
      h_sh[g] = (_Float16)h;
    } else if (g >= HID && g < HID + DIN) {
      int d = g - HID;
      if (t + 1 < T) xin[d] = (_Float16)x[((size_t)b * T + (t + 1)) * DIN + d];
    }
    __syncthreads();
  }
}

// ---------------------------------------------------------------------------
extern "C" void kernel_launch(void* const* d_in, const int* in_sizes, int n_in,
                              void* d_out, int out_size, void* d_ws, size_t ws_size,
                              hipStream_t stream)
{
  const float* x   = (const float*)d_in[0];
  const float* Wih = (const float*)d_in[1];
  const float* Whh = (const float*)d_in[2];
  const float* bih = (const float*)d_in[3];
  const float* bhh = (const float*)d_in[4];
  const float* h0  = (const float*)d_in[5];
  const float* c0  = (const float*)d_in[6];
  float* out = (float*)d_out;

  const int B = in_sizes[5] / HID;
  const int T = in_sizes[0] / (B * DIN);
  const int nrows = B * T;

  const size_t xp_bytes = (size_t)nrows * G4 * sizeof(_Float16);
  if (ws_size >= xp_bytes) {
    _Float16* xp = (_Float16*)d_ws;
    xproj_kernel<<<1024, 512, 0, stream>>>(x, Wih, bih, bhh, xp, nrows);
    lstm_scan3<<<B, 512, 0, stream>>>(Whh, h0, c0, xp, out, T);
  } else {
    lstm_scan_fb<<<B, 512, 0, stream>>>(x, Wih, Whh, bih, bhh, h0, c0, out, T);
  }
}

// Round 5
// 1114.999 us; speedup vs baseline: 1.4599x; 1.4599x over previous
//
#include <hip/hip_runtime.h>

typedef _Float16 half2f __attribute__((ext_vector_type(2)));

#define HID 128   // hidden size
#define G4  512   // 4*HID
#define DIN 64    // input dim

__device__ __forceinline__ float fdot2(half2f a, half2f b, float c) {
  return __builtin_amdgcn_fdot2(a, b, c, false);
}
__device__ __forceinline__ half2f as_h2(unsigned int u) {
  return __builtin_bit_cast(half2f, u);
}
__device__ __forceinline__ half2f mk2(float a, float b) {
  half2f r; r.x = (_Float16)a; r.y = (_Float16)b; return r;
}
__device__ __forceinline__ float sigmoidf_fast(float x) {
  return __builtin_amdgcn_rcpf(1.0f + __expf(-x));
}
__device__ __forceinline__ float tanhf_fast(float x) {
  return 2.0f * __builtin_amdgcn_rcpf(1.0f + __expf(-2.0f * x)) - 1.0f;
}
// DPP quad_perm helpers (immediate ctrl via template)
template <int CTRL>
__device__ __forceinline__ float dpp_add(float x) {
  int m = __builtin_amdgcn_update_dpp(0, __builtin_bit_cast(int, x),
                                      CTRL, 0xF, 0xF, true);
  return x + __builtin_bit_cast(float, m);
}
template <int CTRL>
__device__ __forceinline__ float dpp_get(float x) {
  int m = __builtin_amdgcn_update_dpp(0, __builtin_bit_cast(int, x),
                                      CTRL, 0xF, 0xF, true);
  return __builtin_bit_cast(float, m);
}
#define QP_XOR1 0xB1  // quad_perm [1,0,3,2] -> partner within pair

// ---------------------------------------------------------------------------
// Phase 1: x_proj, stored PERMUTED: [r][unit*4 + gate] (fp16).
// Scan thread (j,kq) reads u32 at index j*2+kq -> gates (2kq,2kq+1) of unit j.
// ---------------------------------------------------------------------------
__global__ __launch_bounds__(512, 2)
void xproj_kernel(const float* __restrict__ x, const float* __restrict__ Wih,
                  const float* __restrict__ bih, const float* __restrict__ bhh,
                  _Float16* __restrict__ xp, int nrows)
{
  const int gp   = threadIdx.x;          // permuted gate index
  const int unit = gp >> 2;
  const int gate = gp & 3;
  const int row  = gate * HID + unit;    // row in W_ih / bias

  half2f wi[32];
  {
    const float4* wr = (const float4*)(Wih + (size_t)row * DIN);
#pragma unroll
    for (int q = 0; q < 16; q++) {
      float4 v = wr[q];
      wi[2 * q + 0] = mk2(v.x, v.y);
      wi[2 * q + 1] = mk2(v.z, v.w);
    }
  }
  const float bias = bih[row] + bhh[row];

  __shared__ __align__(16) _Float16 xin[8 * DIN];

  const int rows_per_block = (nrows + (int)gridDim.x - 1) / (int)gridDim.x;
  const int r0 = blockIdx.x * rows_per_block;
  const int r1 = (r0 + rows_per_block < nrows) ? (r0 + rows_per_block) : nrows;

  const int rsub = threadIdx.x >> 6;  // 0..7
  const int dd   = threadIdx.x & 63;

  float vld = 0.f;
  if (r0 + rsub < nrows) vld = x[(size_t)(r0 + rsub) * DIN + dd];

  for (int r = r0; r < r1; r += 8) {
    __syncthreads();
    xin[rsub * DIN + dd] = (_Float16)vld;
    __syncthreads();
    int rn = r + 8 + rsub;
    if (rn < nrows) vld = x[(size_t)rn * DIN + dd];

    const uint4* xi4 = (const uint4*)xin;
#pragma unroll
    for (int k = 0; k < 8; k++) {
      if (r + k >= r1) break;
      const uint4* rowp = xi4 + k * (DIN / 8);
      float a[4] = {bias, 0.f, 0.f, 0.f};
#pragma unroll
      for (int q = 0; q < 8; q++) {
        uint4 hv = rowp[q];
        a[q & 3] = fdot2(as_h2(hv.x), wi[4 * q + 0], a[q & 3]);
        a[q & 3] = fdot2(as_h2(hv.y), wi[4 * q + 1], a[q & 3]);
        a[q & 3] = fdot2(as_h2(hv.z), wi[4 * q + 2], a[q & 3]);
        a[q & 3] = fdot2(as_h2(hv.w), wi[4 * q + 3], a[q & 3]);
      }
      xp[(size_t)(r + k) * G4 + gp] = (_Float16)(a[0] + a[1] + a[2] + a[3]);
    }
  }
}

// one uint4 worth of h (8 halves) into 4 gate chains
#define DOT16(vv, A0, A1, A2, A3, base)                                   \
  do {                                                                    \
    A0 = fdot2(as_h2((vv).x), w0[(base) + 0], A0);                        \
    A1 = fdot2(as_h2((vv).x), w1[(base) + 0], A1);                        \
    A2 = fdot2(as_h2((vv).x), w2[(base) + 0], A2);                        \
    A3 = fdot2(as_h2((vv).x), w3[(base) + 0], A3);                        \
    A0 = fdot2(as_h2((vv).y), w0[(base) + 1], A0);                        \
    A1 = fdot2(as_h2((vv).y), w1[(base) + 1], A1);                        \
    A2 = fdot2(as_h2((vv).y), w2[(base) + 1], A2);                        \
    A3 = fdot2(as_h2((vv).y), w3[(base) + 1], A3);                        \
    A0 = fdot2(as_h2((vv).z), w0[(base) + 2], A0);                        \
    A1 = fdot2(as_h2((vv).z), w1[(base) + 2], A1);                        \
    A2 = fdot2(as_h2((vv).z), w2[(base) + 2], A2);                        \
    A3 = fdot2(as_h2((vv).z), w3[(base) + 2], A3);                        \
    A0 = fdot2(as_h2((vv).w), w0[(base) + 3], A0);                        \
    A1 = fdot2(as_h2((vv).w), w1[(base) + 3], A1);                        \
    A2 = fdot2(as_h2((vv).w), w2[(base) + 3], A2);                        \
    A3 = fdot2(as_h2((vv).w), w3[(base) + 3], A3);                        \
  } while (0)

// ---------------------------------------------------------------------------
// Phase 2: scan. 64 blocks x 256 threads (round-2 proven structure).
// Thread (j = tid>>1, kq = tid&1): 4 gates of unit j over K-half kq.
// Upgrades vs round 2: 8 acc chains, 8 named LDS reads (early-start dots),
// xp prefetch depth 2, split activations (kq0: sig,sig / kq1: tanh,sig)
// + one DPP pair-swap. One LDS round-trip + one barrier per step.
// ---------------------------------------------------------------------------
__global__ __launch_bounds__(256, 1)
void lstm_scan4(const float* __restrict__ Whh,
                const float* __restrict__ h0, const float* __restrict__ c0,
                const _Float16* __restrict__ xp,
                float* __restrict__ out, int T)
{
  const int tid = threadIdx.x;
  const int j   = tid >> 1;
  const int kq  = tid & 1;
  const int b   = blockIdx.x;

  // W_hh rows gate*128+j, columns [64*kq, 64*kq+64) -> 4 x 32 half2
  half2f w0[32], w1[32], w2[32], w3[32];
  {
    const float4* r0 = (const float4*)(Whh + ((size_t)(0 * HID + j)) * HID + kq * 64);
    const float4* r1 = (const float4*)(Whh + ((size_t)(1 * HID + j)) * HID + kq * 64);
    const float4* r2 = (const float4*)(Whh + ((size_t)(2 * HID + j)) * HID + kq * 64);
    const float4* r3 = (const float4*)(Whh + ((size_t)(3 * HID + j)) * HID + kq * 64);
#pragma unroll
    for (int q = 0; q < 16; q++) {
      float4 v;
      v = r0[q]; w0[2 * q] = mk2(v.x, v.y); w0[2 * q + 1] = mk2(v.z, v.w);
      v = r1[q]; w1[2 * q] = mk2(v.x, v.y); w1[2 * q + 1] = mk2(v.z, v.w);
      v = r2[q]; w2[2 * q] = mk2(v.x, v.y); w2[2 * q + 1] = mk2(v.z, v.w);
      v = r3[q]; w3[2 * q] = mk2(v.x, v.y); w3[2 * q + 1] = mk2(v.z, v.w);
    }
  }

  __shared__ __align__(16) _Float16 h_sh[2][HID];

  float c = c0[(size_t)b * HID + j];
  if (kq == 0) h_sh[0][j] = (_Float16)h0[(size_t)b * HID + j];
  __syncthreads();

  const unsigned int* xp32 = (const unsigned int*)xp;   // u32 = 2 fp16 gates
  const size_t xbase = (size_t)b * T * 256 + (size_t)j * 2 + kq;
  unsigned int xv  = xp32[xbase];
  unsigned int xv1 = (T > 1) ? xp32[xbase + 256] : 0u;

  // per-lane activation constants: kq0 first act = sigmoid, kq1 = tanh
  const float kk = kq ? -2.f : -1.f;
  const float mm = kq ?  2.f :  1.f;
  const float bb = kq ? -1.f :  0.f;

  const _Float16* rb = h_sh[0];
  _Float16*       wb = h_sh[1];

  for (int t = 0; t < T; ++t) {
    unsigned int xv2 = 0;
    if (t + 2 < T) xv2 = xp32[xbase + (size_t)(t + 2) * 256];

    // my K-half of h: 8 named ds_read_b128, consumed in issue order
    const uint4* h4 = (const uint4*)(rb + kq * 64);
    uint4 v0 = h4[0], v1 = h4[1], v2 = h4[2], v3 = h4[3];
    uint4 v4 = h4[4], v5 = h4[5], v6 = h4[6], v7 = h4[7];

    float a0a = 0.f, a1a = 0.f, a2a = 0.f, a3a = 0.f;
    float a0b = 0.f, a1b = 0.f, a2b = 0.f, a3b = 0.f;
    DOT16(v0, a0a, a1a, a2a, a3a, 0);
    DOT16(v1, a0b, a1b, a2b, a3b, 4);
    DOT16(v2, a0a, a1a, a2a, a3a, 8);
    DOT16(v3, a0b, a1b, a2b, a3b, 12);
    DOT16(v4, a0a, a1a, a2a, a3a, 16);
    DOT16(v5, a0b, a1b, a2b, a3b, 20);
    DOT16(v6, a0a, a1a, a2a, a3a, 24);
    DOT16(v7, a0b, a1b, a2b, a3b, 28);

    float A0 = a0a + a0b;
    float A1 = a1a + a1b;
    float A2 = a2a + a2b;
    float A3 = a3a + a3b;

    // add x_proj: lane kq holds gates (2kq, 2kq+1) of unit j
    {
      half2f xh = as_h2(xv);
      float x0 = (float)xh.x, x1 = (float)xh.y;
      if (kq == 0) { A0 += x0; A1 += x1; }
      else         { A2 += x0; A3 += x1; }
    }

    // pair combine (K-half partials) via DPP
    A0 = dpp_add<QP_XOR1>(A0);
    A1 = dpp_add<QP_XOR1>(A1);
    A2 = dpp_add<QP_XOR1>(A2);
    A3 = dpp_add<QP_XOR1>(A3);

    // split activations: kq0 computes i,f (sig,sig); kq1 computes g,o (tanh,sig)
    float x1v = kq ? A2 : A0;
    float x2v = kq ? A3 : A1;
    float act1 = fmaf(mm, __builtin_amdgcn_rcpf(1.0f + __expf(kk * x1v)), bb);
    float act2 = sigmoidf_fast(x2v);
    // swap with pair partner
    float p1 = dpp_get<QP_XOR1>(act1);
    float p2 = dpp_get<QP_XOR1>(act2);
    float gi = kq ? p1 : act1;
    float gf = kq ? p2 : act2;
    float gg = kq ? act1 : p1;
    float go = kq ? act2 : p2;

    c = fmaf(gf, c, gi * gg);           // replicated per pair (bit-identical)
    float h = go * tanhf_fast(c);

    if (kq == 0) wb[j] = (_Float16)h;
    else         out[((size_t)b * T + t) * HID + j] = h;
    __syncthreads();                    // single barrier per step
    const _Float16* tmp = rb; rb = wb; wb = (_Float16*)tmp;
    xv = xv1; xv1 = xv2;
  }
}

// ---------------------------------------------------------------------------
// Fallback (ws too small): inline x-proj, round-1 structure.
// ---------------------------------------------------------------------------
__global__ __launch_bounds__(512, 2)
void lstm_scan_fb(const float* __restrict__ x, const float* __restrict__ Wih,
                  const float* __restrict__ Whh,
                  const float* __restrict__ bih, const float* __restrict__ bhh,
                  const float* __restrict__ h0, const float* __restrict__ c0,
                  float* __restrict__ out, int T)
{
  const int g = threadIdx.x;
  const int b = blockIdx.x;

  half2f w[64];
  {
    const float4* wr = (const float4*)(Whh + (size_t)g * HID);
#pragma unroll
    for (int q = 0; q < 32; q++) {
      float4 v = wr[q];
      w[2 * q + 0] = mk2(v.x, v.y);
      w[2 * q + 1] = mk2(v.z, v.w);
    }
  }
  half2f wi[32];
  float bias;
  {
    const float4* wr = (const float4*)(Wih + (size_t)g * DIN);
#pragma unroll
    for (int q = 0; q < 16; q++) {
      float4 v = wr[q];
      wi[2 * q + 0] = mk2(v.x, v.y);
      wi[2 * q + 1] = mk2(v.z, v.w);
    }
    bias = bih[g] + bhh[g];
  }

  __shared__ __align__(16) _Float16 h_sh[HID];
  __shared__ __align__(16) _Float16 xin[DIN];
  __shared__ float pre[G4];

  float c = 0.f;
  if (g < HID) {
    c = c0[(size_t)b * HID + g];
    h_sh[g] = (_Float16)h0[(size_t)b * HID + g];
  }
  if (g < DIN) xin[g] = (_Float16)x[((size_t)b * T) * DIN + g];
  __syncthreads();

  const bool is_tanh_gate = (g >= 2 * HID) && (g < 3 * HID);

  for (int t = 0; t < T; ++t) {
    float a[4] = {0.f, 0.f, 0.f, 0.f};
    const uint4* h4 = (const uint4*)h_sh;
#pragma unroll
    for (int q = 0; q < 16; q++) {
      uint4 hv = h4[q];
      a[q & 3] = fdot2(as_h2(hv.x), w[4 * q + 0], a[q & 3]);
      a[q & 3] = fdot2(as_h2(hv.y), w[4 * q + 1], a[q & 3]);
      a[q & 3] = fdot2(as_h2(hv.z), w[4 * q + 2], a[q & 3]);
      a[q & 3] = fdot2(as_h2(hv.w), w[4 * q + 3], a[q & 3]);
    }
    const uint4* x4 = (const uint4*)xin;
#pragma unroll
    for (int q = 0; q < 8; q++) {
      uint4 hv = x4[q];
      a[q & 3] = fdot2(as_h2(hv.x), wi[4 * q + 0], a[q & 3]);
      a[q & 3] = fdot2(as_h2(hv.y), wi[4 * q + 1], a[q & 3]);
      a[q & 3] = fdot2(as_h2(hv.z), wi[4 * q + 2], a[q & 3]);
      a[q & 3] = fdot2(as_h2(hv.w), wi[4 * q + 3], a[q & 3]);
    }
    float preact = a[0] + a[1] + a[2] + a[3] + bias;
    float act = is_tanh_gate ? tanhf_fast(preact) : sigmoidf_fast(preact);
    pre[g] = act;
    __syncthreads();

    if (g < HID) {
      float i  = pre[g];
      float f  = pre[g + HID];
      float gg = pre[g + 2 * HID];
      float o  = pre[g + 3 * HID];
      c = f * c + i * gg;
      float h = o * tanhf_fast(c);
      out[((size_t)b * T + t) * HID + g] = h;
      h_sh[g] = (_Float16)h;
    } else if (g >= HID && g < HID + DIN) {
      int d = g - HID;
      if (t + 1 < T) xin[d] = (_Float16)x[((size_t)b * T + (t + 1)) * DIN + d];
    }
    __syncthreads();
  }
}

// ---------------------------------------------------------------------------
extern "C" void kernel_launch(void* const* d_in, const int* in_sizes, int n_in,
                              void* d_out, int out_size, void* d_ws, size_t ws_size,
                              hipStream_t stream)
{
  const float* x   = (const float*)d_in[0];
  const float* Wih = (const float*)d_in[1];
  const float* Whh = (const float*)d_in[2];
  const float* bih = (const float*)d_in[3];
  const float* bhh = (const float*)d_in[4];
  const float* h0  = (const float*)d_in[5];
  const float* c0  = (const float*)d_in[6];
  float* out = (float*)d_out;

  const int B = in_sizes[5] / HID;
  const int T = in_sizes[0] / (B * DIN);
  const int nrows = B * T;

  const size_t xp_bytes = (size_t)nrows * G4 * sizeof(_Float16);
  if (ws_size >= xp_bytes) {
    _Float16* xp = (_Float16*)d_ws;
    xproj_kernel<<<1024, 512, 0, stream>>>(x, Wih, bih, bhh, xp, nrows);
    lstm_scan4<<<B, 256, 0, stream>>>(Whh, h0, c0, xp, out, T);
  } else {
    lstm_scan_fb<<<B, 512, 0, stream>>>(x, Wih, Whh, bih, bhh, h0, c0, out, T);
  }
}

// Round 6
// 1091.911 us; speedup vs baseline: 1.4908x; 1.0211x over previous
//
#include <hip/hip_runtime.h>

typedef _Float16 half2f __attribute__((ext_vector_type(2)));

#define HID 128   // hidden size
#define G4  512   // 4*HID
#define DIN 64    // input dim

__device__ __forceinline__ float fdot2(half2f a, half2f b, float c) {
  return __builtin_amdgcn_fdot2(a, b, c, false);
}
__device__ __forceinline__ half2f as_h2(unsigned int u) {
  return __builtin_bit_cast(half2f, u);
}
__device__ __forceinline__ half2f mk2(float a, float b) {
  half2f r; r.x = (_Float16)a; r.y = (_Float16)b; return r;
}
__device__ __forceinline__ float sigmoidf_fast(float x) {
  return __builtin_amdgcn_rcpf(1.0f + __expf(-x));
}
__device__ __forceinline__ float tanhf_fast(float x) {
  return 2.0f * __builtin_amdgcn_rcpf(1.0f + __expf(-2.0f * x)) - 1.0f;
}
// DPP quad_perm helper (immediate ctrl via template)
template <int CTRL>
__device__ __forceinline__ float dpp_add(float x) {
  int m = __builtin_amdgcn_update_dpp(0, __builtin_bit_cast(int, x),
                                      CTRL, 0xF, 0xF, true);
  return x + __builtin_bit_cast(float, m);
}
#define QP_XOR1 0xB1  // quad_perm [1,0,3,2] -> partner within pair

// Barrier that does NOT drain vmcnt: outstanding global prefetch loads stay
// in flight across steps. lgkmcnt(0) guarantees all my DS ops completed
// before the barrier (h_sh is double-buffered, so one barrier per step is
// sufficient). Memory-clobber asm on both sides pins LDS op ordering.
__device__ __forceinline__ void barrier_lgkm() {
  asm volatile("s_waitcnt lgkmcnt(0)" ::: "memory");
  __builtin_amdgcn_s_barrier();
  asm volatile("" ::: "memory");
}

// ---------------------------------------------------------------------------
// Phase 1: x_proj, stored PERMUTED: [r][unit*4 + gate] (fp16).
// Scan thread (j,kq) reads u32 at index j*2+kq -> gates (2kq,2kq+1) of unit j.
// ---------------------------------------------------------------------------
__global__ __launch_bounds__(512, 2)
void xproj_kernel(const float* __restrict__ x, const float* __restrict__ Wih,
                  const float* __restrict__ bih, const float* __restrict__ bhh,
                  _Float16* __restrict__ xp, int nrows)
{
  const int gp   = threadIdx.x;          // permuted gate index
  const int unit = gp >> 2;
  const int gate = gp & 3;
  const int row  = gate * HID + unit;    // row in W_ih / bias

  half2f wi[32];
  {
    const float4* wr = (const float4*)(Wih + (size_t)row * DIN);
#pragma unroll
    for (int q = 0; q < 16; q++) {
      float4 v = wr[q];
      wi[2 * q + 0] = mk2(v.x, v.y);
      wi[2 * q + 1] = mk2(v.z, v.w);
    }
  }
  const float bias = bih[row] + bhh[row];

  __shared__ __align__(16) _Float16 xin[8 * DIN];

  const int rows_per_block = (nrows + (int)gridDim.x - 1) / (int)gridDim.x;
  const int r0 = blockIdx.x * rows_per_block;
  const int r1 = (r0 + rows_per_block < nrows) ? (r0 + rows_per_block) : nrows;

  const int rsub = threadIdx.x >> 6;  // 0..7
  const int dd   = threadIdx.x & 63;

  float vld = 0.f;
  if (r0 + rsub < nrows) vld = x[(size_t)(r0 + rsub) * DIN + dd];

  for (int r = r0; r < r1; r += 8) {
    barrier_lgkm();                        // prev chunk reads done (lgkm only)
    xin[rsub * DIN + dd] = (_Float16)vld;
    barrier_lgkm();
    // prefetch next chunk while computing this one (stays in flight across
    // the lgkm-only barriers)
    int rn = r + 8 + rsub;
    if (rn < nrows) vld = x[(size_t)rn * DIN + dd];

    const uint4* xi4 = (const uint4*)xin;
#pragma unroll
    for (int k = 0; k < 8; k++) {
      if (r + k >= r1) break;
      const uint4* rowp = xi4 + k * (DIN / 8);
      float a[4] = {bias, 0.f, 0.f, 0.f};
#pragma unroll
      for (int q = 0; q < 8; q++) {
        uint4 hv = rowp[q];
        a[q & 3] = fdot2(as_h2(hv.x), wi[4 * q + 0], a[q & 3]);
        a[q & 3] = fdot2(as_h2(hv.y), wi[4 * q + 1], a[q & 3]);
        a[q & 3] = fdot2(as_h2(hv.z), wi[4 * q + 2], a[q & 3]);
        a[q & 3] = fdot2(as_h2(hv.w), wi[4 * q + 3], a[q & 3]);
      }
      xp[(size_t)(r + k) * G4 + gp] = (_Float16)(a[0] + a[1] + a[2] + a[3]);
    }
  }
}

// ---------------------------------------------------------------------------
// Phase 2: scan. 64 blocks x 256 threads (round-2 proven structure/codegen).
// Thread (j = tid>>1, kq = tid&1): 4 gates of unit j over K-half kq.
// Changes vs round 2: (a) lgkm-only barrier so the xp prefetch is never
// drained by the per-step barrier; (b) prefetch depth 2 (counted vmcnt).
// ---------------------------------------------------------------------------
__global__ __launch_bounds__(256, 1)
void lstm_scan5(const float* __restrict__ Whh,
                const float* __restrict__ h0, const float* __restrict__ c0,
                const _Float16* __restrict__ xp,
                float* __restrict__ out, int T)
{
  const int tid = threadIdx.x;
  const int j   = tid >> 1;
  const int kq  = tid & 1;
  const int b   = blockIdx.x;

  // W_hh rows gate*128+j, columns [64*kq, 64*kq+64) -> 4 x 32 half2
  half2f w0[32], w1[32], w2[32], w3[32];
  {
    const float4* r0 = (const float4*)(Whh + ((size_t)(0 * HID + j)) * HID + kq * 64);
    const float4* r1 = (const float4*)(Whh + ((size_t)(1 * HID + j)) * HID + kq * 64);
    const float4* r2 = (const float4*)(Whh + ((size_t)(2 * HID + j)) * HID + kq * 64);
    const float4* r3 = (const float4*)(Whh + ((size_t)(3 * HID + j)) * HID + kq * 64);
#pragma unroll
    for (int q = 0; q < 16; q++) {
      float4 v;
      v = r0[q]; w0[2 * q] = mk2(v.x, v.y); w0[2 * q + 1] = mk2(v.z, v.w);
      v = r1[q]; w1[2 * q] = mk2(v.x, v.y); w1[2 * q + 1] = mk2(v.z, v.w);
      v = r2[q]; w2[2 * q] = mk2(v.x, v.y); w2[2 * q + 1] = mk2(v.z, v.w);
      v = r3[q]; w3[2 * q] = mk2(v.x, v.y); w3[2 * q + 1] = mk2(v.z, v.w);
    }
  }

  __shared__ __align__(16) _Float16 h_sh[2][HID];

  float c = c0[(size_t)b * HID + j];
  if (kq == 0) h_sh[0][j] = (_Float16)h0[(size_t)b * HID + j];
  __syncthreads();

  const unsigned int* xp32 = (const unsigned int*)xp;   // u32 = 2 fp16 gates
  const size_t xbase = (size_t)b * T * 256 + (size_t)j * 2 + kq;
  unsigned int xv  = xp32[xbase];
  unsigned int xv1 = (T > 1) ? xp32[xbase + 256] : 0u;

  const _Float16* rb = h_sh[0];
  _Float16*       wb = h_sh[1];

  for (int t = 0; t < T; ++t) {
    unsigned int xv2 = 0;
    if (t + 2 < T) xv2 = xp32[xbase + (size_t)(t + 2) * 256];

    // read my K-half of h: 8x ds_read_b128, all in flight at once
    uint4 hv[8];
    const uint4* h4 = (const uint4*)(rb + kq * 64);
#pragma unroll
    for (int q = 0; q < 8; q++) hv[q] = h4[q];

    float a0 = 0.f, a1 = 0.f, a2 = 0.f, a3 = 0.f;
#pragma unroll
    for (int q = 0; q < 8; q++) {
      unsigned int d0 = hv[q].x, d1 = hv[q].y, d2 = hv[q].z, d3 = hv[q].w;
      a0 = fdot2(as_h2(d0), w0[4 * q + 0], a0);
      a1 = fdot2(as_h2(d0), w1[4 * q + 0], a1);
      a2 = fdot2(as_h2(d0), w2[4 * q + 0], a2);
      a3 = fdot2(as_h2(d0), w3[4 * q + 0], a3);
      a0 = fdot2(as_h2(d1), w0[4 * q + 1], a0);
      a1 = fdot2(as_h2(d1), w1[4 * q + 1], a1);
      a2 = fdot2(as_h2(d1), w2[4 * q + 1], a2);
      a3 = fdot2(as_h2(d1), w3[4 * q + 1], a3);
      a0 = fdot2(as_h2(d2), w0[4 * q + 2], a0);
      a1 = fdot2(as_h2(d2), w1[4 * q + 2], a1);
      a2 = fdot2(as_h2(d2), w2[4 * q + 2], a2);
      a3 = fdot2(as_h2(d2), w3[4 * q + 2], a3);
      a0 = fdot2(as_h2(d3), w0[4 * q + 3], a0);
      a1 = fdot2(as_h2(d3), w1[4 * q + 3], a1);
      a2 = fdot2(as_h2(d3), w2[4 * q + 3], a2);
      a3 = fdot2(as_h2(d3), w3[4 * q + 3], a3);
    }

    // add x_proj: lane kq holds gates (2kq, 2kq+1) of unit j
    {
      half2f xh = as_h2(xv);
      float x0 = (float)xh.x, x1 = (float)xh.y;
      if (kq == 0) { a0 += x0; a1 += x1; }
      else         { a2 += x0; a3 += x1; }
    }

    // pair combine (K-half partials) via DPP — no LDS, no barrier
    a0 = dpp_add<QP_XOR1>(a0);
    a1 = dpp_add<QP_XOR1>(a1);
    a2 = dpp_add<QP_XOR1>(a2);
    a3 = dpp_add<QP_XOR1>(a3);

    float i  = sigmoidf_fast(a0);
    float f  = sigmoidf_fast(a1);
    float gg = tanhf_fast(a2);
    float o  = sigmoidf_fast(a3);
    c = f * c + i * gg;                 // c replicated on both lanes
    float h = o * tanhf_fast(c);

    if (kq == 0) {
      wb[j] = (_Float16)h;
      out[((size_t)b * T + t) * HID + j] = h;
    }
    barrier_lgkm();                     // single barrier, vmcnt NOT drained
    const _Float16* tmp = rb; rb = wb; wb = (_Float16*)tmp;
    xv = xv1; xv1 = xv2;
  }
}

// ---------------------------------------------------------------------------
// Fallback (ws too small): inline x-proj, round-1 structure.
// ---------------------------------------------------------------------------
__global__ __launch_bounds__(512, 2)
void lstm_scan_fb(const float* __restrict__ x, const float* __restrict__ Wih,
                  const float* __restrict__ Whh,
                  const float* __restrict__ bih, const float* __restrict__ bhh,
                  const float* __restrict__ h0, const float* __restrict__ c0,
                  float* __restrict__ out, int T)
{
  const int g = threadIdx.x;
  const int b = blockIdx.x;

  half2f w[64];
  {
    const float4* wr = (const float4*)(Whh + (size_t)g * HID);
#pragma unroll
    for (int q = 0; q < 32; q++) {
      float4 v = wr[q];
      w[2 * q + 0] = mk2(v.x, v.y);
      w[2 * q + 1] = mk2(v.z, v.w);
    }
  }
  half2f wi[32];
  float bias;
  {
    const float4* wr = (const float4*)(Wih + (size_t)g * DIN);
#pragma unroll
    for (int q = 0; q < 16; q++) {
      float4 v = wr[q];
      wi[2 * q + 0] = mk2(v.x, v.y);
      wi[2 * q + 1] = mk2(v.z, v.w);
    }
    bias = bih[g] + bhh[g];
  }

  __shared__ __align__(16) _Float16 h_sh[HID];
  __shared__ __align__(16) _Float16 xin[DIN];
  __shared__ float pre[G4];

  float c = 0.f;
  if (g < HID) {
    c = c0[(size_t)b * HID + g];
    h_sh[g] = (_Float16)h0[(size_t)b * HID + g];
  }
  if (g < DIN) xin[g] = (_Float16)x[((size_t)b * T) * DIN + g];
  __syncthreads();

  const bool is_tanh_gate = (g >= 2 * HID) && (g < 3 * HID);

  for (int t = 0; t < T; ++t) {
    float a[4] = {0.f, 0.f, 0.f, 0.f};
    const uint4* h4 = (const uint4*)h_sh;
#pragma unroll
    for (int q = 0; q < 16; q++) {
      uint4 hv = h4[q];
      a[q & 3] = fdot2(as_h2(hv.x), w[4 * q + 0], a[q & 3]);
      a[q & 3] = fdot2(as_h2(hv.y), w[4 * q + 1], a[q & 3]);
      a[q & 3] = fdot2(as_h2(hv.z), w[4 * q + 2], a[q & 3]);
      a[q & 3] = fdot2(as_h2(hv.w), w[4 * q + 3], a[q & 3]);
    }
    const uint4* x4 = (const uint4*)xin;
#pragma unroll
    for (int q = 0; q < 8; q++) {
      uint4 hv = x4[q];
      a[q & 3] = fdot2(as_h2(hv.x), wi[4 * q + 0], a[q & 3]);
      a[q & 3] = fdot2(as_h2(hv.y), wi[4 * q + 1], a[q & 3]);
      a[q & 3] = fdot2(as_h2(hv.z), wi[4 * q + 2], a[q & 3]);
      a[q & 3] = fdot2(as_h2(hv.w), wi[4 * q + 3], a[q & 3]);
    }
    float preact = a[0] + a[1] + a[2] + a[3] + bias;
    float act = is_tanh_gate ? tanhf_fast(preact) : sigmoidf_fast(preact);
    pre[g] = act;
    __syncthreads();

    if (g < HID) {
      float i  = pre[g];
      float f  = pre[g + HID];
      float gg = pre[g + 2 * HID];
      float o  = pre[g + 3 * HID];
      c = f * c + i * gg;
      float h = o * tanhf_fast(c);
      out[((size_t)b * T + t) * HID + g] = h;
      h_sh[g] = (_Float16)h;
    } else if (g >= HID && g < HID + DIN) {
      int d = g - HID;
      if (t + 1 < T) xin[d] = (_Float16)x[((size_t)b * T + (t + 1)) * DIN + d];
    }
    __syncthreads();
  }
}

// ---------------------------------------------------------------------------
extern "C" void kernel_launch(void* const* d_in, const int* in_sizes, int n_in,
                              void* d_out, int out_size, void* d_ws, size_t ws_size,
                              hipStream_t stream)
{
  const float* x   = (const float*)d_in[0];
  const float* Wih = (const float*)d_in[1];
  const float* Whh = (const float*)d_in[2];
  const float* bih = (const float*)d_in[3];
  const float* bhh = (const float*)d_in[4];
  const float* h0  = (const float*)d_in[5];
  const float* c0  = (const float*)d_in[6];
  float* out = (float*)d_out;

  const int B = in_sizes[5] / HID;
  const int T = in_sizes[0] / (B * DIN);
  const int nrows = B * T;

  const size_t xp_bytes = (size_t)nrows * G4 * sizeof(_Float16);
  if (ws_size >= xp_bytes) {
    _Float16* xp = (_Float16*)d_ws;
    xproj_kernel<<<1024, 512, 0, stream>>>(x, Wih, bih, bhh, xp, nrows);
    lstm_scan5<<<B, 256, 0, stream>>>(Whh, h0, c0, xp, out, T);
  } else {
    lstm_scan_fb<<<B, 512, 0, stream>>>(x, Wih, Whh, bih, bhh, h0, c0, out, T);
  }
}